// Round 5
// baseline (306.432 us; speedup 1.0000x reference)
//
#include <hip/hip_runtime.h>
#include <hip/hip_bf16.h>
#include <math.h>

// Problem constants
#define B_  16
#define N_  1024
#define E_  512
#define H_  8

typedef __attribute__((ext_vector_type(8)))  __bf16 bf16x8;
typedef __attribute__((ext_vector_type(4)))  float  f32x4;
typedef __attribute__((ext_vector_type(16))) float  f32x16;
typedef __attribute__((ext_vector_type(4)))  unsigned int u32x4;

struct alignas(16) bf8pack { __hip_bfloat16 v[8]; };
struct alignas(8)  bf4pack { __hip_bfloat16 v[4]; };

static __device__ __forceinline__ float bf2f(__hip_bfloat16 x) { return __bfloat162float(x); }
static __device__ __forceinline__ __hip_bfloat16 f2bf(float x) { return __float2bfloat16(x); }

static __device__ __forceinline__ unsigned pkbf(float lo, float hi) {
    unsigned r;
    asm("v_cvt_pk_bf16_f32 %0, %1, %2" : "=v"(r) : "v"(lo), "v"(hi));
    return r;
}
// v_permlane32_swap_b32 a, b:  a' = [a.lo32, b.lo32], b' = [a.hi32, b.hi32]
static __device__ __forceinline__ void swap32(unsigned &a, unsigned &b) {
    asm("v_permlane32_swap_b32 %0, %1" : "+v"(a), "+v"(b));
}
#define MFMA32(a, b, c) __builtin_amdgcn_mfma_f32_32x32x16_bf16((a), (b), (c), 0, 0, 0)
#define MFMA16(a, b, c) __builtin_amdgcn_mfma_f32_16x16x32_bf16((a), (b), (c), 0, 0, 0)

// ---------------------------------------------------------------------------
// K0: build orthogonal RBS matrix per head -> worth_t[h][e][d] bf16 (SCL folded)
//     and transpose Wv -> wvt[h][e][d] bf16. 8 blocks x 64 threads.
// ---------------------------------------------------------------------------
__global__ __launch_bounds__(64) void k_worth(const float* __restrict__ phi,
                                              const float* __restrict__ Wv,
                                              __hip_bfloat16* __restrict__ worth_t,
                                              __hip_bfloat16* __restrict__ wvt) {
    const float SCL = 0.18033688011112042f;  // log2(e)/8, folds softmax scale
    __shared__ float W[64 * 65];
    int h = blockIdx.x;
    int t = threadIdx.x;  // column index e
    for (int i = 0; i < 64; ++i) W[i * 65 + t] = (i == t) ? 1.0f : 0.0f;
    for (int g = 0; g < 125; ++g) {
        int k = (g < 63) ? g : (124 - g);
        float ph = phi[h * 125 + g];
        float c = cosf(ph), s = sinf(ph);
        float a  = W[k * 65 + t];
        float b  = W[(k + 1) * 65 + t];
        W[k * 65 + t]       =  c * a + s * b;
        W[(k + 1) * 65 + t] = -s * a + c * b;
    }
    for (int d = 0; d < 64; ++d)
        worth_t[h * 4096 + t * 64 + d] = f2bf(W[d * 65 + t] * SCL);
    for (int d = 0; d < 64; ++d)
        wvt[h * 4096 + t * 64 + d] = f2bf(Wv[h * 4096 + d * 64 + t]);
}

// ---------------------------------------------------------------------------
// K0b: LDS-tiled transpose W1,W2 (f32 [in][out]) -> bf16 [out][in].
// Grid (64 tiles, 2 matrices), 256 threads. Coalesced 16B loads and stores.
// ---------------------------------------------------------------------------
__global__ __launch_bounds__(256) void k_transpose(const float* __restrict__ W1,
                                                   const float* __restrict__ W2,
                                                   __hip_bfloat16* __restrict__ w1t,
                                                   __hip_bfloat16* __restrict__ w2t) {
    const float* src = blockIdx.y ? W2 : W1;
    __hip_bfloat16* dst = blockIdx.y ? w2t : w1t;
    int i0 = (blockIdx.x & 7) * 64, o0 = (blockIdx.x >> 3) * 64;
    int tid = threadIdx.x;
    __shared__ float ts[64][65];
    int r = tid >> 4, c4 = (tid & 15) * 4;
#pragma unroll
    for (int j4 = 0; j4 < 4; ++j4) {
        float4 v = *reinterpret_cast<const float4*>(&src[(size_t)(i0 + r + 16 * j4) * 512 + o0 + c4]);
        ts[r + 16 * j4][c4 + 0] = v.x; ts[r + 16 * j4][c4 + 1] = v.y;
        ts[r + 16 * j4][c4 + 2] = v.z; ts[r + 16 * j4][c4 + 3] = v.w;
    }
    __syncthreads();
    int o = tid >> 3, cg = tid & 7;
#pragma unroll
    for (int half = 0; half < 2; ++half) {
        int oo = o + 32 * half;
        bf8pack p;
#pragma unroll
        for (int j = 0; j < 8; ++j) p.v[j] = f2bf(ts[cg * 8 + j][oo]);
        *reinterpret_cast<bf8pack*>(&dst[(size_t)(o0 + oo) * 512 + i0 + cg * 8]) = p;
    }
}

// ---------------------------------------------------------------------------
// K1/K4: LayerNorm over last dim 512 -> bf16 out. Wave per row. T = f32|bf16 in.
// ---------------------------------------------------------------------------
template <typename T>
__global__ __launch_bounds__(256) void k_ln(const T* __restrict__ in,
                                            __hip_bfloat16* __restrict__ out) {
    int w = threadIdx.x >> 6, l = threadIdx.x & 63;
    size_t row = (size_t)blockIdx.x * 4 + w;
    float vv[8];
    if constexpr (sizeof(T) == 4) {
        const float* p = (const float*)in + row * 512 + l * 8;
        float4 v0 = *reinterpret_cast<const float4*>(p);
        float4 v1 = *reinterpret_cast<const float4*>(p + 4);
        vv[0]=v0.x; vv[1]=v0.y; vv[2]=v0.z; vv[3]=v0.w;
        vv[4]=v1.x; vv[5]=v1.y; vv[6]=v1.z; vv[7]=v1.w;
    } else {
        const __hip_bfloat16* p = (const __hip_bfloat16*)in + row * 512 + l * 8;
        bf16x8 u = *reinterpret_cast<const bf16x8*>(p);
#pragma unroll
        for (int j = 0; j < 8; ++j) vv[j] = (float)u[j];
    }
    float s = 0.f, sq = 0.f;
#pragma unroll
    for (int j = 0; j < 8; ++j) { s += vv[j]; sq += vv[j] * vv[j]; }
#pragma unroll
    for (int o = 32; o >= 1; o >>= 1) { s += __shfl_xor(s, o); sq += __shfl_xor(sq, o); }
    float mean = s * (1.0f / 512.0f);
    float var  = sq * (1.0f / 512.0f) - mean * mean;
    float rstd = rsqrtf(var + 1e-5f);
    bf8pack ob;
#pragma unroll
    for (int j = 0; j < 8; ++j) ob.v[j] = f2bf((vv[j] - mean) * rstd);
    *reinterpret_cast<bf8pack*>(out + row * 512 + l * 8) = ob;
}

// ---------------------------------------------------------------------------
// K2: per-head projections via MFMA.
//  xw[b][h][n][d]: A=worth_t(rows e), B=xn(rows n) -> C col=n,row=e -> 8B stores
//  vt[b][h][d][n]: A=xn(rows n),  B=wvt(rows e)    -> C col=e,row=n -> 8B stores
// ---------------------------------------------------------------------------
__global__ __launch_bounds__(256) void k_proj(const __hip_bfloat16* __restrict__ xn,
                                              const __hip_bfloat16* __restrict__ worth_t,
                                              const __hip_bfloat16* __restrict__ wvt,
                                              const float* __restrict__ bv,
                                              __hip_bfloat16* __restrict__ xw,
                                              __hip_bfloat16* __restrict__ vt) {
    int h = blockIdx.y, rt = blockIdx.x;
    int tid = threadIdx.x, w = tid >> 6, l = tid & 63;
    int lr = l & 15, lg = l >> 4;
    int nw = rt * 64 + w * 16;          // global row base for this wave
    int b  = (rt * 64) >> 10;
    int n0 = (rt * 64) & 1023;
    size_t bh = (size_t)b * H_ + h;

    const __hip_bfloat16* xp = xn + (size_t)(nw + lr) * 512 + h * 64 + lg * 8;
    bf16x8 xf0 = *reinterpret_cast<const bf16x8*>(xp);
    bf16x8 xf1 = *reinterpret_cast<const bf16x8*>(xp + 32);

    f32x4 accw[4] = {}, accv[4] = {};
#pragma unroll
    for (int g = 0; g < 4; ++g) {
        const __hip_bfloat16* wp = worth_t + h * 4096 + (g * 16 + lr) * 64 + lg * 8;
        accw[g] = MFMA16(*reinterpret_cast<const bf16x8*>(wp), xf0, accw[g]);
        accw[g] = MFMA16(*reinterpret_cast<const bf16x8*>(wp + 32), xf1, accw[g]);
        const __hip_bfloat16* vp = wvt + h * 4096 + (g * 16 + lr) * 64 + lg * 8;
        accv[g] = MFMA16(xf0, *reinterpret_cast<const bf16x8*>(vp), accv[g]);
        accv[g] = MFMA16(xf1, *reinterpret_cast<const bf16x8*>(vp + 32), accv[g]);
    }
#pragma unroll
    for (int g = 0; g < 4; ++g) {
        bf4pack pw;
#pragma unroll
        for (int r = 0; r < 4; ++r) pw.v[r] = f2bf(accw[g][r]);
        *reinterpret_cast<bf4pack*>(xw + (bh * N_ + n0 + w * 16 + lr) * 64 + g * 16 + lg * 4) = pw;
        float bb = bv[h * 64 + g * 16 + lr];
        bf4pack pv;
#pragma unroll
        for (int r = 0; r < 4; ++r) pv.v[r] = f2bf(accv[g][r] + bb);
        *reinterpret_cast<bf4pack*>(vt + (bh * 64 + g * 16 + lr) * N_ + n0 + w * 16 + lg * 4) = pv;
    }
}

// ---------------------------------------------------------------------------
// K3: attention, no-LDS variant. 4 waves (QBLK=128), 32 q-rows/wave.
// K/V frags loaded directly from global (L2-resident per XCD: grid h-fastest
// puts all q-tiles/batches of a head on one XCD; K/V per (b,h) = 256 KB).
// No barriers anywhere -> waves drift freely; setprio(1) guards MFMA clusters.
// Swapped QK^T 32x32x16: lane owns q=lane&31; softmax lane-local, no max
// (LN'd inputs bound |S|). P->A-frags via cvt_pk+permlane32_swap.
// Epilogue: per-head LN(attn+xh)+x -> res bf16.
// ---------------------------------------------------------------------------
__global__ __launch_bounds__(256, 4) void k_attn(const __hip_bfloat16* __restrict__ xn,
                                                 const __hip_bfloat16* __restrict__ xw,
                                                 const __hip_bfloat16* __restrict__ vt,
                                                 const float* __restrict__ x,
                                                 __hip_bfloat16* __restrict__ res) {
    int h = blockIdx.x, b = blockIdx.z;
    int tid = threadIdx.x;
    int w = tid >> 6, l = tid & 63;
    int lq = l & 31, hi = l >> 5;
    int q0 = blockIdx.y * 128 + w * 32;
    size_t bh = (size_t)b * H_ + h;

    __shared__ float lred[4][32];

    // Q fragments (B operand): row q0+lq, k = kd*16 + 8*hi + j. Pre-scaled.
    const __hip_bfloat16* qp = xw + (bh * N_ + q0 + lq) * 64 + 8 * hi;
    bf16x8 qf0 = *reinterpret_cast<const bf16x8*>(qp);
    bf16x8 qf1 = *reinterpret_cast<const bf16x8*>(qp + 16);
    bf16x8 qf2 = *reinterpret_cast<const bf16x8*>(qp + 32);
    bf16x8 qf3 = *reinterpret_cast<const bf16x8*>(qp + 48);

    const __hip_bfloat16* kp = xn + ((size_t)b * N_ + lq) * 512 + h * 64 + 8 * hi;
    const __hip_bfloat16* vp = vt + (bh * 64 + lq) * N_ + 8 * hi;

    f32x16 o0 = {}, o1 = {};
    float l_run = 0.f;

    for (int m0 = 0; m0 < N_; m0 += 64) {
        const __hip_bfloat16* kr = kp + (size_t)m0 * 512;
        // ---- S^T = mfma(K, Q) ----
        f32x16 s0 = {}, s1 = {};
        __builtin_amdgcn_s_setprio(1);
#pragma unroll
        for (int kd = 0; kd < 4; ++kd) {
            bf16x8 qf = (kd == 0) ? qf0 : (kd == 1) ? qf1 : (kd == 2) ? qf2 : qf3;
            bf16x8 ka0 = *reinterpret_cast<const bf16x8*>(kr + kd * 16);
            bf16x8 ka1 = *reinterpret_cast<const bf16x8*>(kr + 32 * 512 + kd * 16);
            s0 = MFMA32(ka0, qf, s0);
            s1 = MFMA32(ka1, qf, s1);
        }
        __builtin_amdgcn_s_setprio(0);
        // ---- P = exp2(S), accumulate l ----
#pragma unroll
        for (int i = 0; i < 16; ++i) {
            s0[i] = __builtin_amdgcn_exp2f(s0[i]);
            s1[i] = __builtin_amdgcn_exp2f(s1[i]);
        }
        float ls = 0.f;
#pragma unroll
        for (int i = 0; i < 16; ++i) ls += s0[i] + s1[i];
        l_run += ls;
        // ---- redistribute P -> PV A-frags (cvt_pk + permlane32_swap) ----
        bf16x8 pa[4];
        {
            unsigned u0 = pkbf(s0[0], s0[1]), u1 = pkbf(s0[2], s0[3]);
            unsigned u2 = pkbf(s0[4], s0[5]), u3 = pkbf(s0[6], s0[7]);
            swap32(u0, u2); swap32(u1, u3);
            u32x4 uu = {u0, u1, u2, u3};
            pa[0] = __builtin_bit_cast(bf16x8, uu);
        }
        {
            unsigned u0 = pkbf(s0[8], s0[9]),   u1 = pkbf(s0[10], s0[11]);
            unsigned u2 = pkbf(s0[12], s0[13]), u3 = pkbf(s0[14], s0[15]);
            swap32(u0, u2); swap32(u1, u3);
            u32x4 uu = {u0, u1, u2, u3};
            pa[1] = __builtin_bit_cast(bf16x8, uu);
        }
        {
            unsigned u0 = pkbf(s1[0], s1[1]), u1 = pkbf(s1[2], s1[3]);
            unsigned u2 = pkbf(s1[4], s1[5]), u3 = pkbf(s1[6], s1[7]);
            swap32(u0, u2); swap32(u1, u3);
            u32x4 uu = {u0, u1, u2, u3};
            pa[2] = __builtin_bit_cast(bf16x8, uu);
        }
        {
            unsigned u0 = pkbf(s1[8], s1[9]),   u1 = pkbf(s1[10], s1[11]);
            unsigned u2 = pkbf(s1[12], s1[13]), u3 = pkbf(s1[14], s1[15]);
            swap32(u0, u2); swap32(u1, u3);
            u32x4 uu = {u0, u1, u2, u3};
            pa[3] = __builtin_bit_cast(bf16x8, uu);
        }
        // ---- O += P @ V ----
        const __hip_bfloat16* vr = vp + m0;
        __builtin_amdgcn_s_setprio(1);
#pragma unroll
        for (int ks = 0; ks < 4; ++ks) {
            bf16x8 v0 = *reinterpret_cast<const bf16x8*>(vr + ks * 16);
            bf16x8 v1 = *reinterpret_cast<const bf16x8*>(vr + 32 * N_ + ks * 16);
            o0 = MFMA32(pa[ks], v0, o0);
            o1 = MFMA32(pa[ks], v1, o1);
        }
        __builtin_amdgcn_s_setprio(0);
    }

    // ---- finalize: per-head LN(attn + xh) + x -> res (bf16) ----
    float lt = l_run + __shfl_xor(l_run, 32);
    if (hi == 0) lred[w][lq] = 1.0f / lt;   // wave-local LDS roundtrip
#pragma unroll
    for (int r = 0; r < 16; ++r) {
        int qr = (r & 3) + 8 * (r >> 2) + 4 * hi;
        float li = lred[w][qr];
        size_t base = ((size_t)b * N_ + q0 + qr) * 512 + h * 64;
        float t0 = o0[r] * li + bf2f(xn[base + lq]);
        float t1 = o1[r] * li + bf2f(xn[base + 32 + lq]);
        float s1v = t0 + t1, s2v = t0 * t0 + t1 * t1;
#pragma unroll
        for (int off = 16; off >= 1; off >>= 1) { s1v += __shfl_xor(s1v, off); s2v += __shfl_xor(s2v, off); }
        float mean = s1v * (1.0f / 64.0f);
        float var  = s2v * (1.0f / 64.0f) - mean * mean;
        float rstd = rsqrtf(var + 1e-5f);
        res[base + lq]      = f2bf((t0 - mean) * rstd + x[base + lq]);
        res[base + 32 + lq] = f2bf((t1 - mean) * rstd + x[base + 32 + lq]);
    }
}

// ---------------------------------------------------------------------------
// K5/K6: GEMM 16384x512x512, no-LDS. Block = 128x64 tile, 4 waves x 32 rows.
// B-frags direct from global (Bt = 0.5 MB, L2-resident). Grid rt-fastest:
// rt%8 -> XCD, so each A row-panel is fetched from HBM by one XCD only.
// MODE 0: out = gelu(A@Bt^T + bias) -> bf16.  MODE 1: out = A@Bt^T+bias+res -> f32.
// ---------------------------------------------------------------------------
template <int MODE>
__global__ __launch_bounds__(256, 4) void k_gemm(const __hip_bfloat16* __restrict__ A,
                                                 const __hip_bfloat16* __restrict__ Bt,
                                                 const float* __restrict__ bias,
                                                 const __hip_bfloat16* __restrict__ resid,
                                                 __hip_bfloat16* __restrict__ outb,
                                                 float* __restrict__ outf) {
    int m0 = blockIdx.x * 128, nn0 = blockIdx.y * 64;
    int tid = threadIdx.x, w = tid >> 6, l = tid & 63;
    int lr = l & 15, lg = l >> 4;
    f32x4 acc0[4] = {}, acc1[4] = {};
    const __hip_bfloat16* ap0 = A + (size_t)(m0 + w * 32 + lr) * 512 + lg * 8;
    const __hip_bfloat16* ap1 = ap0 + 16 * 512;
    const __hip_bfloat16* bp = Bt + (size_t)(nn0 + lr) * 512 + lg * 8;
#pragma unroll 4
    for (int k = 0; k < 512; k += 32) {
        bf16x8 a0 = *reinterpret_cast<const bf16x8*>(ap0 + k);
        bf16x8 a1 = *reinterpret_cast<const bf16x8*>(ap1 + k);
        __builtin_amdgcn_s_setprio(1);
#pragma unroll
        for (int g = 0; g < 4; ++g) {
            bf16x8 bf = *reinterpret_cast<const bf16x8*>(bp + (size_t)g * 16 * 512 + k);
            acc0[g] = MFMA16(a0, bf, acc0[g]);
            acc1[g] = MFMA16(a1, bf, acc1[g]);
        }
        __builtin_amdgcn_s_setprio(0);
    }
#pragma unroll
    for (int g = 0; g < 4; ++g) {
        int col = nn0 + g * 16 + lr;
        float bb = bias[col];
#pragma unroll
        for (int r = 0; r < 4; ++r) {
            int row0 = m0 + w * 32 + lg * 4 + r;
            float v0 = acc0[g][r] + bb;
            float v1 = acc1[g][r] + bb;
            if (MODE == 0) {
                float g0 = 0.5f * v0 * (1.0f + erff(v0 * 0.70710678118654752f));
                float g1 = 0.5f * v1 * (1.0f + erff(v1 * 0.70710678118654752f));
                outb[(size_t)row0 * 512 + col] = f2bf(g0);
                outb[(size_t)(row0 + 16) * 512 + col] = f2bf(g1);
            } else {
                size_t i0 = (size_t)row0 * 512 + col;
                size_t i1 = (size_t)(row0 + 16) * 512 + col;
                outf[i0] = v0 + bf2f(resid[i0]);
                outf[i1] = v1 + bf2f(resid[i1]);
            }
        }
    }
}

// ---------------------------------------------------------------------------
extern "C" void kernel_launch(void* const* d_in, const int* in_sizes, int n_in,
                              void* d_out, int out_size, void* d_ws, size_t ws_size,
                              hipStream_t stream) {
    const float* x   = (const float*)d_in[0];
    const float* Wv  = (const float*)d_in[1];
    const float* bv  = (const float*)d_in[2];
    const float* phi = (const float*)d_in[3];
    const float* W1  = (const float*)d_in[4];
    const float* b1  = (const float*)d_in[5];
    const float* W2  = (const float*)d_in[6];
    const float* b2  = (const float*)d_in[7];
    float* out = (float*)d_out;

    char* ws = (char*)d_ws;
    __hip_bfloat16* worth_t = (__hip_bfloat16*)(ws + 0);         // 64 KB
    __hip_bfloat16* wvt     = (__hip_bfloat16*)(ws + 65536);     // 64 KB
    __hip_bfloat16* w1t     = (__hip_bfloat16*)(ws + 131072);    // 512 KB
    __hip_bfloat16* w2t     = (__hip_bfloat16*)(ws + 655360);    // 512 KB
    __hip_bfloat16* xn      = (__hip_bfloat16*)(ws + 1179648);   // 16 MB
    __hip_bfloat16* xw      = (__hip_bfloat16*)(ws + 17956864);  // 16 MB
    __hip_bfloat16* vt      = (__hip_bfloat16*)(ws + 34734080);  // 16 MB
    __hip_bfloat16* res     = (__hip_bfloat16*)(ws + 51511296);  // 16 MB
    __hip_bfloat16* xn2     = (__hip_bfloat16*)(ws + 68288512);  // 16 MB
    __hip_bfloat16* y1      = (__hip_bfloat16*)(ws + 85065728);  // 16 MB

    k_worth<<<dim3(8), dim3(64), 0, stream>>>(phi, Wv, worth_t, wvt);
    k_transpose<<<dim3(64, 2), dim3(256), 0, stream>>>(W1, W2, w1t, w2t);
    k_ln<float><<<dim3(4096), dim3(256), 0, stream>>>(x, xn);                  // norm1
    k_proj<<<dim3(256, 8), dim3(256), 0, stream>>>(xn, worth_t, wvt, bv, xw, vt);
    k_attn<<<dim3(8, 8, 16), dim3(256), 0, stream>>>(xn, xw, vt, x, res);
    k_ln<__hip_bfloat16><<<dim3(4096), dim3(256), 0, stream>>>(res, xn2);      // norm2
    k_gemm<0><<<dim3(128, 8), dim3(256), 0, stream>>>(xn2, w1t, b1, nullptr, y1, nullptr);
    k_gemm<1><<<dim3(128, 8), dim3(256), 0, stream>>>(y1, w2t, b2, res, nullptr, out);
}

// Round 6
// 207.594 us; speedup vs baseline: 1.4761x; 1.4761x over previous
//
#include <hip/hip_runtime.h>
#include <hip/hip_bf16.h>
#include <math.h>

// Problem constants
#define B_  16
#define N_  1024
#define E_  512
#define H_  8

typedef __attribute__((ext_vector_type(8)))  __bf16 bf16x8;
typedef __attribute__((ext_vector_type(4)))  float  f32x4;
typedef __attribute__((ext_vector_type(16))) float  f32x16;
typedef __attribute__((ext_vector_type(4)))  unsigned int u32x4;

struct alignas(16) bf8pack { __hip_bfloat16 v[8]; };
struct alignas(8)  bf4pack { __hip_bfloat16 v[4]; };

static __device__ __forceinline__ float bf2f(__hip_bfloat16 x) { return __bfloat162float(x); }
static __device__ __forceinline__ __hip_bfloat16 f2bf(float x) { return __float2bfloat16(x); }

static __device__ __forceinline__ unsigned pkbf(float lo, float hi) {
    unsigned r;
    asm("v_cvt_pk_bf16_f32 %0, %1, %2" : "=v"(r) : "v"(lo), "v"(hi));
    return r;
}
// v_permlane32_swap_b32 a, b:  a' = [a.lo32, b.lo32], b' = [a.hi32, b.hi32]
static __device__ __forceinline__ void swap32(unsigned &a, unsigned &b) {
    asm("v_permlane32_swap_b32 %0, %1" : "+v"(a), "+v"(b));
}
// async global->LDS, 16B per lane. LDS dest is wave-uniform base + lane*16.
static __device__ __forceinline__ void gload16(const __hip_bfloat16* g, __hip_bfloat16* l) {
    __builtin_amdgcn_global_load_lds(
        (const __attribute__((address_space(1))) unsigned*)g,
        (__attribute__((address_space(3))) unsigned*)l, 16, 0, 0);
}
#define MFMA32(a, b, c) __builtin_amdgcn_mfma_f32_32x32x16_bf16((a), (b), (c), 0, 0, 0)
#define MFMA16(a, b, c) __builtin_amdgcn_mfma_f32_16x16x32_bf16((a), (b), (c), 0, 0, 0)

// ---------------------------------------------------------------------------
// K0: build orthogonal RBS matrix per head -> worth_t[h][e][d] bf16 (SCL folded)
//     and transpose Wv -> wvt[h][e][d] bf16. 8 blocks x 64 threads.
// ---------------------------------------------------------------------------
__global__ __launch_bounds__(64) void k_worth(const float* __restrict__ phi,
                                              const float* __restrict__ Wv,
                                              __hip_bfloat16* __restrict__ worth_t,
                                              __hip_bfloat16* __restrict__ wvt) {
    const float SCL = 0.18033688011112042f;  // log2(e)/8, folds softmax scale
    __shared__ float W[64 * 65];
    int h = blockIdx.x;
    int t = threadIdx.x;  // column index e
    for (int i = 0; i < 64; ++i) W[i * 65 + t] = (i == t) ? 1.0f : 0.0f;
    for (int g = 0; g < 125; ++g) {
        int k = (g < 63) ? g : (124 - g);
        float ph = phi[h * 125 + g];
        float c = cosf(ph), s = sinf(ph);
        float a  = W[k * 65 + t];
        float b  = W[(k + 1) * 65 + t];
        W[k * 65 + t]       =  c * a + s * b;
        W[(k + 1) * 65 + t] = -s * a + c * b;
    }
    for (int d = 0; d < 64; ++d)
        worth_t[h * 4096 + t * 64 + d] = f2bf(W[d * 65 + t] * SCL);
    for (int d = 0; d < 64; ++d)
        wvt[h * 4096 + t * 64 + d] = f2bf(Wv[h * 4096 + d * 64 + t]);
}

// ---------------------------------------------------------------------------
// K0b: LDS-tiled transpose W1,W2 (f32 [in][out]) -> bf16 [out][in].
// ---------------------------------------------------------------------------
__global__ __launch_bounds__(256) void k_transpose(const float* __restrict__ W1,
                                                   const float* __restrict__ W2,
                                                   __hip_bfloat16* __restrict__ w1t,
                                                   __hip_bfloat16* __restrict__ w2t) {
    const float* src = blockIdx.y ? W2 : W1;
    __hip_bfloat16* dst = blockIdx.y ? w2t : w1t;
    int i0 = (blockIdx.x & 7) * 64, o0 = (blockIdx.x >> 3) * 64;
    int tid = threadIdx.x;
    __shared__ float ts[64][65];
    int r = tid >> 4, c4 = (tid & 15) * 4;
#pragma unroll
    for (int j4 = 0; j4 < 4; ++j4) {
        float4 v = *reinterpret_cast<const float4*>(&src[(size_t)(i0 + r + 16 * j4) * 512 + o0 + c4]);
        ts[r + 16 * j4][c4 + 0] = v.x; ts[r + 16 * j4][c4 + 1] = v.y;
        ts[r + 16 * j4][c4 + 2] = v.z; ts[r + 16 * j4][c4 + 3] = v.w;
    }
    __syncthreads();
    int o = tid >> 3, cg = tid & 7;
#pragma unroll
    for (int half = 0; half < 2; ++half) {
        int oo = o + 32 * half;
        bf8pack p;
#pragma unroll
        for (int j = 0; j < 8; ++j) p.v[j] = f2bf(ts[cg * 8 + j][oo]);
        *reinterpret_cast<bf8pack*>(&dst[(size_t)(o0 + oo) * 512 + i0 + cg * 8]) = p;
    }
}

// ---------------------------------------------------------------------------
// K1/K4: LayerNorm over last dim 512 -> bf16 out. Wave per row. T = f32|bf16 in.
// ---------------------------------------------------------------------------
template <typename T>
__global__ __launch_bounds__(256) void k_ln(const T* __restrict__ in,
                                            __hip_bfloat16* __restrict__ out) {
    int w = threadIdx.x >> 6, l = threadIdx.x & 63;
    size_t row = (size_t)blockIdx.x * 4 + w;
    float vv[8];
    if constexpr (sizeof(T) == 4) {
        const float* p = (const float*)in + row * 512 + l * 8;
        float4 v0 = *reinterpret_cast<const float4*>(p);
        float4 v1 = *reinterpret_cast<const float4*>(p + 4);
        vv[0]=v0.x; vv[1]=v0.y; vv[2]=v0.z; vv[3]=v0.w;
        vv[4]=v1.x; vv[5]=v1.y; vv[6]=v1.z; vv[7]=v1.w;
    } else {
        const __hip_bfloat16* p = (const __hip_bfloat16*)in + row * 512 + l * 8;
        bf16x8 u = *reinterpret_cast<const bf16x8*>(p);
#pragma unroll
        for (int j = 0; j < 8; ++j) vv[j] = (float)u[j];
    }
    float s = 0.f, sq = 0.f;
#pragma unroll
    for (int j = 0; j < 8; ++j) { s += vv[j]; sq += vv[j] * vv[j]; }
#pragma unroll
    for (int o = 32; o >= 1; o >>= 1) { s += __shfl_xor(s, o); sq += __shfl_xor(sq, o); }
    float mean = s * (1.0f / 512.0f);
    float var  = sq * (1.0f / 512.0f) - mean * mean;
    float rstd = rsqrtf(var + 1e-5f);
    bf8pack ob;
#pragma unroll
    for (int j = 0; j < 8; ++j) ob.v[j] = f2bf((vv[j] - mean) * rstd);
    *reinterpret_cast<bf8pack*>(out + row * 512 + l * 8) = ob;
}

// ---------------------------------------------------------------------------
// K2: per-head projections via MFMA.
// ---------------------------------------------------------------------------
__global__ __launch_bounds__(256) void k_proj(const __hip_bfloat16* __restrict__ xn,
                                              const __hip_bfloat16* __restrict__ worth_t,
                                              const __hip_bfloat16* __restrict__ wvt,
                                              const float* __restrict__ bv,
                                              __hip_bfloat16* __restrict__ xw,
                                              __hip_bfloat16* __restrict__ vt) {
    int h = blockIdx.y, rt = blockIdx.x;
    int tid = threadIdx.x, w = tid >> 6, l = tid & 63;
    int lr = l & 15, lg = l >> 4;
    int nw = rt * 64 + w * 16;
    int b  = (rt * 64) >> 10;
    int n0 = (rt * 64) & 1023;
    size_t bh = (size_t)b * H_ + h;

    const __hip_bfloat16* xp = xn + (size_t)(nw + lr) * 512 + h * 64 + lg * 8;
    bf16x8 xf0 = *reinterpret_cast<const bf16x8*>(xp);
    bf16x8 xf1 = *reinterpret_cast<const bf16x8*>(xp + 32);

    f32x4 accw[4] = {}, accv[4] = {};
#pragma unroll
    for (int g = 0; g < 4; ++g) {
        const __hip_bfloat16* wp = worth_t + h * 4096 + (g * 16 + lr) * 64 + lg * 8;
        accw[g] = MFMA16(*reinterpret_cast<const bf16x8*>(wp), xf0, accw[g]);
        accw[g] = MFMA16(*reinterpret_cast<const bf16x8*>(wp + 32), xf1, accw[g]);
        const __hip_bfloat16* vp = wvt + h * 4096 + (g * 16 + lr) * 64 + lg * 8;
        accv[g] = MFMA16(xf0, *reinterpret_cast<const bf16x8*>(vp), accv[g]);
        accv[g] = MFMA16(xf1, *reinterpret_cast<const bf16x8*>(vp + 32), accv[g]);
    }
#pragma unroll
    for (int g = 0; g < 4; ++g) {
        bf4pack pw;
#pragma unroll
        for (int r = 0; r < 4; ++r) pw.v[r] = f2bf(accw[g][r]);
        *reinterpret_cast<bf4pack*>(xw + (bh * N_ + n0 + w * 16 + lr) * 64 + g * 16 + lg * 4) = pw;
        float bb = bv[h * 64 + g * 16 + lr];
        bf4pack pv;
#pragma unroll
        for (int r = 0; r < 4; ++r) pv.v[r] = f2bf(accv[g][r] + bb);
        *reinterpret_cast<bf4pack*>(vt + (bh * 64 + g * 16 + lr) * N_ + n0 + w * 16 + lg * 4) = pv;
    }
}

// ---------------------------------------------------------------------------
// K3: attention. 8 waves (512 thr), QBLK=256, KVBLK=64, 4-buffer LDS ring.
// 2-tile software pipeline: at tile t, issue QK^T(t+1) MFMAs (ping-pong S regs)
// before softmax(t) VALU and PV(t) MFMAs -> MFMA pipe and VALU pipe overlap.
// Counted vmcnt(2) + raw barrier once per tile (stage t+3 in flight across it).
// Swapped QK^T 32x32x16: lane owns q=lane&31; softmax lane-local, no max.
// Epilogue: per-head LN(attn+xh)+x -> res bf16.
// ---------------------------------------------------------------------------
__global__ __launch_bounds__(512, 4) void k_attn(const __hip_bfloat16* __restrict__ xn,
                                                 const __hip_bfloat16* __restrict__ xw,
                                                 const __hip_bfloat16* __restrict__ vt,
                                                 const float* __restrict__ x,
                                                 __hip_bfloat16* __restrict__ res) {
    int h = blockIdx.x, b = blockIdx.z;
    int tid = threadIdx.x;
    int w = tid >> 6, l = tid & 63;
    int lq = l & 31, hi = l >> 5;
    int so = lq & 7;
    int q0 = blockIdx.y * 256 + w * 32;
    size_t bh = (size_t)b * H_ + h;

    __shared__ __hip_bfloat16 kb[4][4096];
    __shared__ __hip_bfloat16 vb[4][4096];
    __shared__ float lred[8][32];

    // staging: wave w sources rows w*8..w*8+7 (one gload16 each for K and V)
    int rloc = w * 8 + (l >> 3);
    int gs = ((l & 7) ^ (rloc & 7)) << 3;  // pre-swizzled global col (bf16 units)
    const __hip_bfloat16* ksrc = xn + ((size_t)b * N_ + rloc) * 512 + h * 64 + gs;
    const __hip_bfloat16* vsrc = vt + (bh * 64 + rloc) * N_ + gs;

#define STAGE(t) do { \
        gload16(ksrc + (size_t)(t) * 64 * 512, &kb[(t) & 3][w * 512]); \
        gload16(vsrc + (t) * 64, &vb[(t) & 3][w * 512]); } while (0)
#define TILE_BAR(nvm) do { \
        asm volatile("s_waitcnt vmcnt(" #nvm ")" ::: "memory"); \
        __builtin_amdgcn_s_barrier(); \
        __builtin_amdgcn_sched_barrier(0); } while (0)

    // Q fragments (B operand): row q0+lq, k = kd*16 + 8*hi + j. Pre-scaled.
    const __hip_bfloat16* qp = xw + (bh * N_ + q0 + lq) * 64 + 8 * hi;
    bf16x8 qf0 = *reinterpret_cast<const bf16x8*>(qp);
    bf16x8 qf1 = *reinterpret_cast<const bf16x8*>(qp + 16);
    bf16x8 qf2 = *reinterpret_cast<const bf16x8*>(qp + 32);
    bf16x8 qf3 = *reinterpret_cast<const bf16x8*>(qp + 48);

    f32x16 o0 = {}, o1 = {};
    float l_run = 0.f;

    // QK^T of tile tp1 -> (d0, d1)
    auto qk = [&](int tp1, f32x16& d0, f32x16& d1) {
        const __hip_bfloat16* kc = &kb[tp1 & 3][0];
#pragma unroll
        for (int kd = 0; kd < 4; ++kd) {
            bf16x8 qf = (kd == 0) ? qf0 : (kd == 1) ? qf1 : (kd == 2) ? qf2 : qf3;
            int sl = ((kd * 2 + hi) ^ so) << 3;
            bf16x8 ka0 = *reinterpret_cast<const bf16x8*>(kc + lq * 64 + sl);
            bf16x8 ka1 = *reinterpret_cast<const bf16x8*>(kc + (lq + 32) * 64 + sl);
            d0 = MFMA32(ka0, qf, d0);
            d1 = MFMA32(ka1, qf, d1);
        }
    };
    // softmax(t) + PV(t), consuming (s0, s1) in place
    auto sfmpv = [&](int t, f32x16& s0, f32x16& s1) {
#pragma unroll
        for (int i = 0; i < 16; ++i) {
            s0[i] = __builtin_amdgcn_exp2f(s0[i]);
            s1[i] = __builtin_amdgcn_exp2f(s1[i]);
        }
        float ls = 0.f;
#pragma unroll
        for (int i = 0; i < 16; ++i) ls += s0[i] + s1[i];
        l_run += ls;
        const __hip_bfloat16* vc = &vb[t & 3][0];
        bf16x8 pa[4];
        {
            unsigned u0 = pkbf(s0[0], s0[1]), u1 = pkbf(s0[2], s0[3]);
            unsigned u2 = pkbf(s0[4], s0[5]), u3 = pkbf(s0[6], s0[7]);
            swap32(u0, u2); swap32(u1, u3);
            u32x4 uu = {u0, u1, u2, u3};
            pa[0] = __builtin_bit_cast(bf16x8, uu);
        }
        {
            unsigned u0 = pkbf(s0[8], s0[9]),   u1 = pkbf(s0[10], s0[11]);
            unsigned u2 = pkbf(s0[12], s0[13]), u3 = pkbf(s0[14], s0[15]);
            swap32(u0, u2); swap32(u1, u3);
            u32x4 uu = {u0, u1, u2, u3};
            pa[1] = __builtin_bit_cast(bf16x8, uu);
        }
        {
            unsigned u0 = pkbf(s1[0], s1[1]), u1 = pkbf(s1[2], s1[3]);
            unsigned u2 = pkbf(s1[4], s1[5]), u3 = pkbf(s1[6], s1[7]);
            swap32(u0, u2); swap32(u1, u3);
            u32x4 uu = {u0, u1, u2, u3};
            pa[2] = __builtin_bit_cast(bf16x8, uu);
        }
        {
            unsigned u0 = pkbf(s1[8], s1[9]),   u1 = pkbf(s1[10], s1[11]);
            unsigned u2 = pkbf(s1[12], s1[13]), u3 = pkbf(s1[14], s1[15]);
            swap32(u0, u2); swap32(u1, u3);
            u32x4 uu = {u0, u1, u2, u3};
            pa[3] = __builtin_bit_cast(bf16x8, uu);
        }
#pragma unroll
        for (int ks = 0; ks < 4; ++ks) {
            int sl = ((ks * 2 + hi) ^ so) << 3;
            bf16x8 v0 = *reinterpret_cast<const bf16x8*>(vc + lq * 64 + sl);
            bf16x8 v1 = *reinterpret_cast<const bf16x8*>(vc + (lq + 32) * 64 + sl);
            o0 = MFMA32(pa[ks], v0, o0);
            o1 = MFMA32(pa[ks], v1, o1);
        }
    };

    // ---- prologue: stage 0,1,2; certify 0,1 landed for all waves ----
    STAGE(0); STAGE(1); STAGE(2);
    TILE_BAR(2);

    f32x16 sA0 = {}, sA1 = {}, sB0 = {}, sB1 = {};
    qk(0, sA0, sA1);

    // ---- main: t = 0..11 (even/odd ping-pong), then peel 12..15 ----
    for (int tp = 0; tp < 6; ++tp) {
        int t = 2 * tp;
        STAGE(t + 3);
        qk(t + 1, sB0, sB1);
        sfmpv(t, sA0, sA1);
        sA0 = (f32x16){}; sA1 = (f32x16){};
        TILE_BAR(2);
        STAGE(t + 4);
        qk(t + 2, sA0, sA1);
        sfmpv(t + 1, sB0, sB1);
        sB0 = (f32x16){}; sB1 = (f32x16){};
        TILE_BAR(2);
    }
    // t = 12 (sA holds S(12))
    STAGE(15);
    qk(13, sB0, sB1);
    sfmpv(12, sA0, sA1);
    sA0 = (f32x16){}; sA1 = (f32x16){};
    TILE_BAR(2);
    // t = 13 (no stage; drain remaining)
    qk(14, sA0, sA1);
    sfmpv(13, sB0, sB1);
    sB0 = (f32x16){}; sB1 = (f32x16){};
    TILE_BAR(0);
    // t = 14 (all data landed; no more writes -> no barriers)
    qk(15, sB0, sB1);
    sfmpv(14, sA0, sA1);
    // t = 15
    sfmpv(15, sB0, sB1);

    // ---- finalize: per-head LN(attn + xh) + x -> res (bf16) ----
    float lt = l_run + __shfl_xor(l_run, 32);
    if (hi == 0) lred[w][lq] = 1.0f / lt;   // wave-local LDS roundtrip
#pragma unroll
    for (int r = 0; r < 16; ++r) {
        int qr = (r & 3) + 8 * (r >> 2) + 4 * hi;
        float li = lred[w][qr];
        size_t base = ((size_t)b * N_ + q0 + qr) * 512 + h * 64;
        float t0 = o0[r] * li + bf2f(xn[base + lq]);
        float t1 = o1[r] * li + bf2f(xn[base + 32 + lq]);
        float s1v = t0 + t1, s2v = t0 * t0 + t1 * t1;
#pragma unroll
        for (int off = 16; off >= 1; off >>= 1) { s1v += __shfl_xor(s1v, off); s2v += __shfl_xor(s2v, off); }
        float mean = s1v * (1.0f / 64.0f);
        float var  = s2v * (1.0f / 64.0f) - mean * mean;
        float rstd = rsqrtf(var + 1e-5f);
        res[base + lq]      = f2bf((t0 - mean) * rstd + x[base + lq]);
        res[base + 32 + lq] = f2bf((t1 - mean) * rstd + x[base + 32 + lq]);
    }
#undef STAGE
#undef TILE_BAR
}

// ---------------------------------------------------------------------------
// K5/K6: GEMM 16384x512x512, bf16 MFMA. Block = 128x64 tile, 4 waves x 32 rows.
// Bt panel (64x512 = 64 KB) staged in LDS, 16B-slot XOR swizzle.
// MODE 0: out = gelu(A@Bt^T + bias) -> bf16.  MODE 1: out = A@Bt^T+bias+res -> f32.
// ---------------------------------------------------------------------------
template <int MODE>
__global__ __launch_bounds__(256) void k_gemm(const __hip_bfloat16* __restrict__ A,
                                              const __hip_bfloat16* __restrict__ Bt,
                                              const float* __restrict__ bias,
                                              const __hip_bfloat16* __restrict__ resid,
                                              __hip_bfloat16* __restrict__ outb,
                                              float* __restrict__ outf) {
    int nn0 = blockIdx.x * 64, m0 = blockIdx.y * 128;
    int tid = threadIdx.x, w = tid >> 6, l = tid & 63;
    int lr = l & 15, lg = l >> 4;
    __shared__ __hip_bfloat16 bs[64 * 512];  // 64 KB

#pragma unroll
    for (int i = 0; i < 16; ++i) {
        int row = w * 16 + i;
        gload16(Bt + (size_t)(nn0 + row) * 512 + ((l ^ (row & 7)) << 3),
                &bs[row * 512]);
    }
    __syncthreads();

    f32x4 acc0[4] = {}, acc1[4] = {};
    const __hip_bfloat16* ap0 = A + (size_t)(m0 + w * 32 + lr) * 512 + lg * 8;
    const __hip_bfloat16* ap1 = ap0 + 16 * 512;
#pragma unroll
    for (int k = 0; k < 512; k += 32) {
        bf16x8 a0 = *reinterpret_cast<const bf16x8*>(ap0 + k);
        bf16x8 a1 = *reinterpret_cast<const bf16x8*>(ap1 + k);
#pragma unroll
        for (int g = 0; g < 4; ++g) {
            int row = g * 16 + lr;
            bf16x8 bf = *reinterpret_cast<const bf16x8*>(
                bs + row * 512 + ((((k >> 3) + lg) ^ (row & 7)) << 3));
            acc0[g] = MFMA16(a0, bf, acc0[g]);
            acc1[g] = MFMA16(a1, bf, acc1[g]);
        }
    }
#pragma unroll
    for (int g = 0; g < 4; ++g) {
        int col = nn0 + g * 16 + lr;
        float bb = bias[col];
#pragma unroll
        for (int r = 0; r < 4; ++r) {
            int row0 = m0 + w * 32 + lg * 4 + r;
            float v0 = acc0[g][r] + bb;
            float v1 = acc1[g][r] + bb;
            if (MODE == 0) {
                float g0 = 0.5f * v0 * (1.0f + erff(v0 * 0.70710678118654752f));
                float g1 = 0.5f * v1 * (1.0f + erff(v1 * 0.70710678118654752f));
                outb[(size_t)row0 * 512 + col] = f2bf(g0);
                outb[(size_t)(row0 + 16) * 512 + col] = f2bf(g1);
            } else {
                size_t i0 = (size_t)row0 * 512 + col;
                size_t i1 = (size_t)(row0 + 16) * 512 + col;
                outf[i0] = v0 + bf2f(resid[i0]);
                outf[i1] = v1 + bf2f(resid[i1]);
            }
        }
    }
}

// ---------------------------------------------------------------------------
extern "C" void kernel_launch(void* const* d_in, const int* in_sizes, int n_in,
                              void* d_out, int out_size, void* d_ws, size_t ws_size,
                              hipStream_t stream) {
    const float* x   = (const float*)d_in[0];
    const float* Wv  = (const float*)d_in[1];
    const float* bv  = (const float*)d_in[2];
    const float* phi = (const float*)d_in[3];
    const float* W1  = (const float*)d_in[4];
    const float* b1  = (const float*)d_in[5];
    const float* W2  = (const float*)d_in[6];
    const float* b2  = (const float*)d_in[7];
    float* out = (float*)d_out;

    char* ws = (char*)d_ws;
    __hip_bfloat16* worth_t = (__hip_bfloat16*)(ws + 0);         // 64 KB
    __hip_bfloat16* wvt     = (__hip_bfloat16*)(ws + 65536);     // 64 KB
    __hip_bfloat16* w1t     = (__hip_bfloat16*)(ws + 131072);    // 512 KB
    __hip_bfloat16* w2t     = (__hip_bfloat16*)(ws + 655360);    // 512 KB
    __hip_bfloat16* xn      = (__hip_bfloat16*)(ws + 1179648);   // 16 MB
    __hip_bfloat16* xw      = (__hip_bfloat16*)(ws + 17956864);  // 16 MB
    __hip_bfloat16* vt      = (__hip_bfloat16*)(ws + 34734080);  // 16 MB
    __hip_bfloat16* res     = (__hip_bfloat16*)(ws + 51511296);  // 16 MB
    __hip_bfloat16* xn2     = (__hip_bfloat16*)(ws + 68288512);  // 16 MB
    __hip_bfloat16* y1      = (__hip_bfloat16*)(ws + 85065728);  // 16 MB

    k_worth<<<dim3(8), dim3(64), 0, stream>>>(phi, Wv, worth_t, wvt);
    k_transpose<<<dim3(64, 2), dim3(256), 0, stream>>>(W1, W2, w1t, w2t);
    k_ln<float><<<dim3(4096), dim3(256), 0, stream>>>(x, xn);                  // norm1
    k_proj<<<dim3(256, 8), dim3(256), 0, stream>>>(xn, worth_t, wvt, bv, xw, vt);
    k_attn<<<dim3(8, 4, 16), dim3(512), 0, stream>>>(xn, xw, vt, x, res);
    k_ln<__hip_bfloat16><<<dim3(4096), dim3(256), 0, stream>>>(res, xn2);      // norm2
    k_gemm<0><<<dim3(8, 128), dim3(256), 0, stream>>>(xn2, w1t, b1, nullptr, y1, nullptr);
    k_gemm<1><<<dim3(8, 128), dim3(256), 0, stream>>>(y1, w2t, b2, res, nullptr, out);
}

// Round 7
// 178.477 us; speedup vs baseline: 1.7169x; 1.1631x over previous
//
#include <hip/hip_runtime.h>
#include <hip/hip_bf16.h>
#include <math.h>

// Problem constants
#define B_  16
#define N_  1024
#define E_  512
#define H_  8

typedef __attribute__((ext_vector_type(8)))  __bf16 bf16x8;
typedef __attribute__((ext_vector_type(4)))  float  f32x4;
typedef __attribute__((ext_vector_type(16))) float  f32x16;
typedef __attribute__((ext_vector_type(4)))  unsigned int u32x4;

struct alignas(16) bf8pack { __hip_bfloat16 v[8]; };
struct alignas(8)  bf4pack { __hip_bfloat16 v[4]; };

static __device__ __forceinline__ float bf2f(__hip_bfloat16 x) { return __bfloat162float(x); }
static __device__ __forceinline__ __hip_bfloat16 f2bf(float x) { return __float2bfloat16(x); }

static __device__ __forceinline__ unsigned pkbf(float lo, float hi) {
    unsigned r;
    asm("v_cvt_pk_bf16_f32 %0, %1, %2" : "=v"(r) : "v"(lo), "v"(hi));
    return r;
}
// v_permlane32_swap_b32 a, b:  a' = [a.lo32, b.lo32], b' = [a.hi32, b.hi32]
static __device__ __forceinline__ void swap32(unsigned &a, unsigned &b) {
    asm("v_permlane32_swap_b32 %0, %1" : "+v"(a), "+v"(b));
}
// async global->LDS, 16B per lane. LDS dest is wave-uniform base + lane*16.
static __device__ __forceinline__ void gload16(const __hip_bfloat16* g, __hip_bfloat16* l) {
    __builtin_amdgcn_global_load_lds(
        (const __attribute__((address_space(1))) unsigned*)g,
        (__attribute__((address_space(3))) unsigned*)l, 16, 0, 0);
}
#define MFMA32(a, b, c) __builtin_amdgcn_mfma_f32_32x32x16_bf16((a), (b), (c), 0, 0, 0)
#define MFMA16(a, b, c) __builtin_amdgcn_mfma_f32_16x16x32_bf16((a), (b), (c), 0, 0, 0)

// ---------------------------------------------------------------------------
// K0: build orthogonal RBS matrix per head -> worth_t[h][e][d] bf16 (SCL folded)
//     and transpose Wv -> wvt[h][e][d] bf16. 8 blocks x 64 threads.
// ---------------------------------------------------------------------------
__global__ __launch_bounds__(64) void k_worth(const float* __restrict__ phi,
                                              const float* __restrict__ Wv,
                                              __hip_bfloat16* __restrict__ worth_t,
                                              __hip_bfloat16* __restrict__ wvt) {
    const float SCL = 0.18033688011112042f;  // log2(e)/8, folds softmax scale
    __shared__ float W[64 * 65];
    int h = blockIdx.x;
    int t = threadIdx.x;  // column index e
    for (int i = 0; i < 64; ++i) W[i * 65 + t] = (i == t) ? 1.0f : 0.0f;
    for (int g = 0; g < 125; ++g) {
        int k = (g < 63) ? g : (124 - g);
        float ph = phi[h * 125 + g];
        float c = cosf(ph), s = sinf(ph);
        float a  = W[k * 65 + t];
        float b  = W[(k + 1) * 65 + t];
        W[k * 65 + t]       =  c * a + s * b;
        W[(k + 1) * 65 + t] = -s * a + c * b;
    }
    for (int d = 0; d < 64; ++d)
        worth_t[h * 4096 + t * 64 + d] = f2bf(W[d * 65 + t] * SCL);
    for (int d = 0; d < 64; ++d)
        wvt[h * 4096 + t * 64 + d] = f2bf(Wv[h * 4096 + d * 64 + t]);
}

// ---------------------------------------------------------------------------
// K0b: LDS-tiled transpose W1,W2 (f32 [in][out]) -> bf16 [out][in].
// ---------------------------------------------------------------------------
__global__ __launch_bounds__(256) void k_transpose(const float* __restrict__ W1,
                                                   const float* __restrict__ W2,
                                                   __hip_bfloat16* __restrict__ w1t,
                                                   __hip_bfloat16* __restrict__ w2t) {
    const float* src = blockIdx.y ? W2 : W1;
    __hip_bfloat16* dst = blockIdx.y ? w2t : w1t;
    int i0 = (blockIdx.x & 7) * 64, o0 = (blockIdx.x >> 3) * 64;
    int tid = threadIdx.x;
    __shared__ float ts[64][65];
    int r = tid >> 4, c4 = (tid & 15) * 4;
#pragma unroll
    for (int j4 = 0; j4 < 4; ++j4) {
        float4 v = *reinterpret_cast<const float4*>(&src[(size_t)(i0 + r + 16 * j4) * 512 + o0 + c4]);
        ts[r + 16 * j4][c4 + 0] = v.x; ts[r + 16 * j4][c4 + 1] = v.y;
        ts[r + 16 * j4][c4 + 2] = v.z; ts[r + 16 * j4][c4 + 3] = v.w;
    }
    __syncthreads();
    int o = tid >> 3, cg = tid & 7;
#pragma unroll
    for (int half = 0; half < 2; ++half) {
        int oo = o + 32 * half;
        bf8pack p;
#pragma unroll
        for (int j = 0; j < 8; ++j) p.v[j] = f2bf(ts[cg * 8 + j][oo]);
        *reinterpret_cast<bf8pack*>(&dst[(size_t)(o0 + oo) * 512 + i0 + cg * 8]) = p;
    }
}

// ---------------------------------------------------------------------------
// K1/K4: LayerNorm over last dim 512 -> bf16 out. Wave per row. T = f32|bf16 in.
// ---------------------------------------------------------------------------
template <typename T>
__global__ __launch_bounds__(256) void k_ln(const T* __restrict__ in,
                                            __hip_bfloat16* __restrict__ out) {
    int w = threadIdx.x >> 6, l = threadIdx.x & 63;
    size_t row = (size_t)blockIdx.x * 4 + w;
    float vv[8];
    if constexpr (sizeof(T) == 4) {
        const float* p = (const float*)in + row * 512 + l * 8;
        float4 v0 = *reinterpret_cast<const float4*>(p);
        float4 v1 = *reinterpret_cast<const float4*>(p + 4);
        vv[0]=v0.x; vv[1]=v0.y; vv[2]=v0.z; vv[3]=v0.w;
        vv[4]=v1.x; vv[5]=v1.y; vv[6]=v1.z; vv[7]=v1.w;
    } else {
        const __hip_bfloat16* p = (const __hip_bfloat16*)in + row * 512 + l * 8;
        bf16x8 u = *reinterpret_cast<const bf16x8*>(p);
#pragma unroll
        for (int j = 0; j < 8; ++j) vv[j] = (float)u[j];
    }
    float s = 0.f, sq = 0.f;
#pragma unroll
    for (int j = 0; j < 8; ++j) { s += vv[j]; sq += vv[j] * vv[j]; }
#pragma unroll
    for (int o = 32; o >= 1; o >>= 1) { s += __shfl_xor(s, o); sq += __shfl_xor(sq, o); }
    float mean = s * (1.0f / 512.0f);
    float var  = sq * (1.0f / 512.0f) - mean * mean;
    float rstd = rsqrtf(var + 1e-5f);
    bf8pack ob;
#pragma unroll
    for (int j = 0; j < 8; ++j) ob.v[j] = f2bf((vv[j] - mean) * rstd);
    *reinterpret_cast<bf8pack*>(out + row * 512 + l * 8) = ob;
}

// ---------------------------------------------------------------------------
// K2: per-head projections via MFMA.
// ---------------------------------------------------------------------------
__global__ __launch_bounds__(256) void k_proj(const __hip_bfloat16* __restrict__ xn,
                                              const __hip_bfloat16* __restrict__ worth_t,
                                              const __hip_bfloat16* __restrict__ wvt,
                                              const float* __restrict__ bv,
                                              __hip_bfloat16* __restrict__ xw,
                                              __hip_bfloat16* __restrict__ vt) {
    int h = blockIdx.y, rt = blockIdx.x;
    int tid = threadIdx.x, w = tid >> 6, l = tid & 63;
    int lr = l & 15, lg = l >> 4;
    int nw = rt * 64 + w * 16;
    int b  = (rt * 64) >> 10;
    int n0 = (rt * 64) & 1023;
    size_t bh = (size_t)b * H_ + h;

    const __hip_bfloat16* xp = xn + (size_t)(nw + lr) * 512 + h * 64 + lg * 8;
    bf16x8 xf0 = *reinterpret_cast<const bf16x8*>(xp);
    bf16x8 xf1 = *reinterpret_cast<const bf16x8*>(xp + 32);

    f32x4 accw[4] = {}, accv[4] = {};
#pragma unroll
    for (int g = 0; g < 4; ++g) {
        const __hip_bfloat16* wp = worth_t + h * 4096 + (g * 16 + lr) * 64 + lg * 8;
        accw[g] = MFMA16(*reinterpret_cast<const bf16x8*>(wp), xf0, accw[g]);
        accw[g] = MFMA16(*reinterpret_cast<const bf16x8*>(wp + 32), xf1, accw[g]);
        const __hip_bfloat16* vp = wvt + h * 4096 + (g * 16 + lr) * 64 + lg * 8;
        accv[g] = MFMA16(xf0, *reinterpret_cast<const bf16x8*>(vp), accv[g]);
        accv[g] = MFMA16(xf1, *reinterpret_cast<const bf16x8*>(vp + 32), accv[g]);
    }
#pragma unroll
    for (int g = 0; g < 4; ++g) {
        bf4pack pw;
#pragma unroll
        for (int r = 0; r < 4; ++r) pw.v[r] = f2bf(accw[g][r]);
        *reinterpret_cast<bf4pack*>(xw + (bh * N_ + n0 + w * 16 + lr) * 64 + g * 16 + lg * 4) = pw;
        float bb = bv[h * 64 + g * 16 + lr];
        bf4pack pv;
#pragma unroll
        for (int r = 0; r < 4; ++r) pv.v[r] = f2bf(accv[g][r] + bb);
        *reinterpret_cast<bf4pack*>(vt + (bh * 64 + g * 16 + lr) * N_ + n0 + w * 16 + lg * 4) = pv;
    }
}

// ---------------------------------------------------------------------------
// K3: attention (r4 structure, proven). 8 waves (512 thr), QBLK=256, KVBLK=64.
// Triple-buffered K/V LDS (48 KB), stage t+2 at tile t, counted vmcnt(2) +
// raw barrier (no drain). Swapped QK^T 32x32x16: lane owns q=lane&31;
// softmax lane-local, no max (LN'd inputs bound |S|). setprio(1) around
// MFMA clusters (T5: two independent blocks/CU drift out of phase).
// Epilogue: per-head LN(attn+xh)+x -> res bf16.
// ---------------------------------------------------------------------------
__global__ __launch_bounds__(512, 4) void k_attn(const __hip_bfloat16* __restrict__ xn,
                                                 const __hip_bfloat16* __restrict__ xw,
                                                 const __hip_bfloat16* __restrict__ vt,
                                                 const float* __restrict__ x,
                                                 __hip_bfloat16* __restrict__ res) {
    int h = blockIdx.x, b = blockIdx.z;
    int tid = threadIdx.x;
    int w = tid >> 6, l = tid & 63;
    int lq = l & 31, hi = l >> 5;
    int so = lq & 7;
    int q0 = blockIdx.y * 256 + w * 32;
    size_t bh = (size_t)b * H_ + h;

    __shared__ __hip_bfloat16 kb[3][4096];
    __shared__ __hip_bfloat16 vb[3][4096];
    __shared__ float lred[8][32];

    // staging: wave w sources rows w*8..w*8+7 (one gload16 each for K and V)
    int rloc = w * 8 + (l >> 3);
    int gs = ((l & 7) ^ (rloc & 7)) << 3;  // pre-swizzled global col (bf16 units)
    const __hip_bfloat16* ksrc = xn + ((size_t)b * N_ + rloc) * 512 + h * 64 + gs;
    const __hip_bfloat16* vsrc = vt + (bh * 64 + rloc) * N_ + gs;

#define STAGE(q, m0) do { \
        gload16(ksrc + (size_t)(m0) * 512, &kb[q][w * 512]); \
        gload16(vsrc + (m0), &vb[q][w * 512]); } while (0)
#define TILE_BAR(nvm) do { \
        asm volatile("s_waitcnt vmcnt(" #nvm ")" ::: "memory"); \
        __builtin_amdgcn_s_barrier(); \
        __builtin_amdgcn_sched_barrier(0); } while (0)

    // Q fragments (B operand): row q0+lq, k = kd*16 + 8*hi + j. Pre-scaled.
    const __hip_bfloat16* qp = xw + (bh * N_ + q0 + lq) * 64 + 8 * hi;
    bf16x8 qf0 = *reinterpret_cast<const bf16x8*>(qp);
    bf16x8 qf1 = *reinterpret_cast<const bf16x8*>(qp + 16);
    bf16x8 qf2 = *reinterpret_cast<const bf16x8*>(qp + 32);
    bf16x8 qf3 = *reinterpret_cast<const bf16x8*>(qp + 48);

    f32x16 o0 = {}, o1 = {};
    float l_run = 0.f;

    auto tile_body = [&](int qc) {
        const __hip_bfloat16* kc = &kb[qc][0];
        const __hip_bfloat16* vc = &vb[qc][0];
        f32x16 s0 = {}, s1 = {};
        __builtin_amdgcn_s_setprio(1);
#pragma unroll
        for (int kd = 0; kd < 4; ++kd) {
            bf16x8 qf = (kd == 0) ? qf0 : (kd == 1) ? qf1 : (kd == 2) ? qf2 : qf3;
            int sl = ((kd * 2 + hi) ^ so) << 3;
            bf16x8 ka0 = *reinterpret_cast<const bf16x8*>(kc + lq * 64 + sl);
            bf16x8 ka1 = *reinterpret_cast<const bf16x8*>(kc + (lq + 32) * 64 + sl);
            s0 = MFMA32(ka0, qf, s0);
            s1 = MFMA32(ka1, qf, s1);
        }
        __builtin_amdgcn_s_setprio(0);
#pragma unroll
        for (int i = 0; i < 16; ++i) {
            s0[i] = __builtin_amdgcn_exp2f(s0[i]);
            s1[i] = __builtin_amdgcn_exp2f(s1[i]);
        }
        float ls = 0.f;
#pragma unroll
        for (int i = 0; i < 16; ++i) ls += s0[i] + s1[i];
        l_run += ls;
        bf16x8 pa[4];
        {
            unsigned u0 = pkbf(s0[0], s0[1]), u1 = pkbf(s0[2], s0[3]);
            unsigned u2 = pkbf(s0[4], s0[5]), u3 = pkbf(s0[6], s0[7]);
            swap32(u0, u2); swap32(u1, u3);
            u32x4 uu = {u0, u1, u2, u3};
            pa[0] = __builtin_bit_cast(bf16x8, uu);
        }
        {
            unsigned u0 = pkbf(s0[8], s0[9]),   u1 = pkbf(s0[10], s0[11]);
            unsigned u2 = pkbf(s0[12], s0[13]), u3 = pkbf(s0[14], s0[15]);
            swap32(u0, u2); swap32(u1, u3);
            u32x4 uu = {u0, u1, u2, u3};
            pa[1] = __builtin_bit_cast(bf16x8, uu);
        }
        {
            unsigned u0 = pkbf(s1[0], s1[1]), u1 = pkbf(s1[2], s1[3]);
            unsigned u2 = pkbf(s1[4], s1[5]), u3 = pkbf(s1[6], s1[7]);
            swap32(u0, u2); swap32(u1, u3);
            u32x4 uu = {u0, u1, u2, u3};
            pa[2] = __builtin_bit_cast(bf16x8, uu);
        }
        {
            unsigned u0 = pkbf(s1[8], s1[9]),   u1 = pkbf(s1[10], s1[11]);
            unsigned u2 = pkbf(s1[12], s1[13]), u3 = pkbf(s1[14], s1[15]);
            swap32(u0, u2); swap32(u1, u3);
            u32x4 uu = {u0, u1, u2, u3};
            pa[3] = __builtin_bit_cast(bf16x8, uu);
        }
        __builtin_amdgcn_s_setprio(1);
#pragma unroll
        for (int ks = 0; ks < 4; ++ks) {
            int sl = ((ks * 2 + hi) ^ so) << 3;
            bf16x8 v0 = *reinterpret_cast<const bf16x8*>(vc + lq * 64 + sl);
            bf16x8 v1 = *reinterpret_cast<const bf16x8*>(vc + (lq + 32) * 64 + sl);
            o0 = MFMA32(pa[ks], v0, o0);
            o1 = MFMA32(pa[ks], v1, o1);
        }
        __builtin_amdgcn_s_setprio(0);
    };

    // ---- prologue: stage tiles 0,1; full drain once ----
    STAGE(0, 0);
    STAGE(1, 64);
    TILE_BAR(0);

    int qc = 0;
    for (int t = 0; t < 14; ++t) {
        int qn = qc + 2; if (qn >= 3) qn -= 3;
        STAGE(qn, (t + 2) * 64);
        tile_body(qc);
        TILE_BAR(2);           // tile t+1 landed; t+2's 2 loads stay in flight
        qc = (qc == 2) ? 0 : qc + 1;
    }
    tile_body(qc);             // t = 14 (qc == 2)
    TILE_BAR(0);               // force tile 15 landed
    tile_body(0);              // t = 15

    // ---- finalize: per-head LN(attn + xh) + x -> res (bf16) ----
    float lt = l_run + __shfl_xor(l_run, 32);
    if (hi == 0) lred[w][lq] = 1.0f / lt;   // wave-local LDS roundtrip
#pragma unroll
    for (int r = 0; r < 16; ++r) {
        int qr = (r & 3) + 8 * (r >> 2) + 4 * hi;
        float li = lred[w][qr];
        size_t base = ((size_t)b * N_ + q0 + qr) * 512 + h * 64;
        float t0 = o0[r] * li + bf2f(xn[base + lq]);
        float t1 = o1[r] * li + bf2f(xn[base + 32 + lq]);
        float s1v = t0 + t1, s2v = t0 * t0 + t1 * t1;
#pragma unroll
        for (int off = 16; off >= 1; off >>= 1) { s1v += __shfl_xor(s1v, off); s2v += __shfl_xor(s2v, off); }
        float mean = s1v * (1.0f / 64.0f);
        float var  = s2v * (1.0f / 64.0f) - mean * mean;
        float rstd = rsqrtf(var + 1e-5f);
        res[base + lq]      = f2bf((t0 - mean) * rstd + x[base + lq]);
        res[base + 32 + lq] = f2bf((t1 - mean) * rstd + x[base + 32 + lq]);
    }
#undef STAGE
#undef TILE_BAR
}

// ---------------------------------------------------------------------------
// K5/K6: GEMM 16384x512x512, bf16 MFMA. Block = 128x64 tile, 4 waves x 32 rows.
// Bt panel (64x512 = 64 KB) staged in LDS, 16B-slot XOR swizzle.
// Grid (rt=128, ct=8): XCD = (rt + 128*ct)%8 = rt%8 -> the 8 col-tiles of a
// row-panel share an XCD; per-XCD A strip = 2 MB (L2-resident), A fetched
// from HBM once total. B (0.5 MB) L2-resident everywhere.
// MODE 0: out = gelu(A@Bt^T + bias) -> bf16.  MODE 1: out = A@Bt^T+bias+res -> f32.
// ---------------------------------------------------------------------------
template <int MODE>
__global__ __launch_bounds__(256) void k_gemm(const __hip_bfloat16* __restrict__ A,
                                              const __hip_bfloat16* __restrict__ Bt,
                                              const float* __restrict__ bias,
                                              const __hip_bfloat16* __restrict__ resid,
                                              __hip_bfloat16* __restrict__ outb,
                                              float* __restrict__ outf) {
    int m0 = blockIdx.x * 128, nn0 = blockIdx.y * 64;
    int tid = threadIdx.x, w = tid >> 6, l = tid & 63;
    int lr = l & 15, lg = l >> 4;
    __shared__ __hip_bfloat16 bs[64 * 512];  // 64 KB

#pragma unroll
    for (int i = 0; i < 16; ++i) {
        int row = w * 16 + i;
        gload16(Bt + (size_t)(nn0 + row) * 512 + ((l ^ (row & 7)) << 3),
                &bs[row * 512]);
    }
    __syncthreads();

    f32x4 acc0[4] = {}, acc1[4] = {};
    const __hip_bfloat16* ap0 = A + (size_t)(m0 + w * 32 + lr) * 512 + lg * 8;
    const __hip_bfloat16* ap1 = ap0 + 16 * 512;
#pragma unroll
    for (int k = 0; k < 512; k += 32) {
        bf16x8 a0 = *reinterpret_cast<const bf16x8*>(ap0 + k);
        bf16x8 a1 = *reinterpret_cast<const bf16x8*>(ap1 + k);
#pragma unroll
        for (int g = 0; g < 4; ++g) {
            int row = g * 16 + lr;
            bf16x8 bf = *reinterpret_cast<const bf16x8*>(
                bs + row * 512 + ((((k >> 3) + lg) ^ (row & 7)) << 3));
            acc0[g] = MFMA16(a0, bf, acc0[g]);
            acc1[g] = MFMA16(a1, bf, acc1[g]);
        }
    }
#pragma unroll
    for (int g = 0; g < 4; ++g) {
        int col = nn0 + g * 16 + lr;
        float bb = bias[col];
#pragma unroll
        for (int r = 0; r < 4; ++r) {
            int row0 = m0 + w * 32 + lg * 4 + r;
            float v0 = acc0[g][r] + bb;
            float v1 = acc1[g][r] + bb;
            if (MODE == 0) {
                float g0 = 0.5f * v0 * (1.0f + erff(v0 * 0.70710678118654752f));
                float g1 = 0.5f * v1 * (1.0f + erff(v1 * 0.70710678118654752f));
                outb[(size_t)row0 * 512 + col] = f2bf(g0);
                outb[(size_t)(row0 + 16) * 512 + col] = f2bf(g1);
            } else {
                size_t i0 = (size_t)row0 * 512 + col;
                size_t i1 = (size_t)(row0 + 16) * 512 + col;
                outf[i0] = v0 + bf2f(resid[i0]);
                outf[i1] = v1 + bf2f(resid[i1]);
            }
        }
    }
}

// ---------------------------------------------------------------------------
extern "C" void kernel_launch(void* const* d_in, const int* in_sizes, int n_in,
                              void* d_out, int out_size, void* d_ws, size_t ws_size,
                              hipStream_t stream) {
    const float* x   = (const float*)d_in[0];
    const float* Wv  = (const float*)d_in[1];
    const float* bv  = (const float*)d_in[2];
    const float* phi = (const float*)d_in[3];
    const float* W1  = (const float*)d_in[4];
    const float* b1  = (const float*)d_in[5];
    const float* W2  = (const float*)d_in[6];
    const float* b2  = (const float*)d_in[7];
    float* out = (float*)d_out;

    char* ws = (char*)d_ws;
    __hip_bfloat16* worth_t = (__hip_bfloat16*)(ws + 0);         // 64 KB
    __hip_bfloat16* wvt     = (__hip_bfloat16*)(ws + 65536);     // 64 KB
    __hip_bfloat16* w1t     = (__hip_bfloat16*)(ws + 131072);    // 512 KB
    __hip_bfloat16* w2t     = (__hip_bfloat16*)(ws + 655360);    // 512 KB
    __hip_bfloat16* xn      = (__hip_bfloat16*)(ws + 1179648);   // 16 MB
    __hip_bfloat16* xw      = (__hip_bfloat16*)(ws + 17956864);  // 16 MB
    __hip_bfloat16* vt      = (__hip_bfloat16*)(ws + 34734080);  // 16 MB
    __hip_bfloat16* res     = (__hip_bfloat16*)(ws + 51511296);  // 16 MB
    __hip_bfloat16* xn2     = (__hip_bfloat16*)(ws + 68288512);  // 16 MB
    __hip_bfloat16* y1      = (__hip_bfloat16*)(ws + 85065728);  // 16 MB

    k_worth<<<dim3(8), dim3(64), 0, stream>>>(phi, Wv, worth_t, wvt);
    k_transpose<<<dim3(64, 2), dim3(256), 0, stream>>>(W1, W2, w1t, w2t);
    k_ln<float><<<dim3(4096), dim3(256), 0, stream>>>(x, xn);                  // norm1
    k_proj<<<dim3(256, 8), dim3(256), 0, stream>>>(xn, worth_t, wvt, bv, xw, vt);
    k_attn<<<dim3(8, 4, 16), dim3(512), 0, stream>>>(xn, xw, vt, x, res);
    k_ln<__hip_bfloat16><<<dim3(4096), dim3(256), 0, stream>>>(res, xn2);      // norm2
    k_gemm<0><<<dim3(128, 8), dim3(256), 0, stream>>>(xn2, w1t, b1, nullptr, y1, nullptr);
    k_gemm<1><<<dim3(128, 8), dim3(256), 0, stream>>>(y1, w2t, b2, res, nullptr, out);
}